// Round 1
// baseline (150.489 us; speedup 1.0000x reference)
//
#include <hip/hip_runtime.h>

// PreEncoder float2bit: each input float -> 16 outputs in {-1, +1}.
// The reference's log2/floor/mod arithmetic is equivalent to truncated
// fp16-style bit extraction with wrap-around 5-bit exponent:
//   w = s<<15 | ((E+15)&31)<<10 | (mant23>>13)
// with s = sign(f + 0.001) quirk, zero -> all bits 0,
// NaN -> 0x7E00, +inf -> 0x7C00, -inf -> 0xFC00.
// Each thread produces one float4 of output (4 bits of one input element):
// fully coalesced 16B stores; input load is 4-way broadcast (cache absorbs).

__global__ __launch_bounds__(256) void preencoder_f2b_kernel(
    const float* __restrict__ x, float4* __restrict__ out, int n4) {
  int t = blockIdx.x * blockDim.x + threadIdx.x;
  if (t >= n4) return;

  int i = t >> 2;   // input element
  int c = t & 3;    // which group of 4 bits

  float f = x[i];
  unsigned u = __float_as_uint(f);
  unsigned a = u & 0x7FFFFFFFu;

  unsigned w;
  bool sign_half = false;  // (f + 0.001f) == 0 exactly -> s = 0.5 -> output 0.0

  if (a > 0x7F800000u) {
    // NaN pattern: [0, 1,1,1,1,1, 1, 0 x 9]
    w = 0x7E00u;
  } else if (a == 0x7F800000u) {
    // +/- inf patterns
    w = (u >> 31) ? 0xFC00u : 0x7C00u;
  } else {
    if (a == 0u) {
      // zero: e_sci clamped to -15 -> e_dec = 0, mantissa bits 0
      w = 0u;
    } else {
      int e8 = (int)(a >> 23);
      int E;
      unsigned mant;
      if (e8 != 0) {
        // normal float32
        E = e8 - 127;
        mant = a & 0x7FFFFFu;
      } else {
        // subnormal: normalize exactly (floor(log2) is exact here)
        int p = 31 - __clz((int)a);  // MSB bit position (<= 22)
        E = p - 149;
        mant = (a << (23 - p)) & 0x7FFFFFu;
      }
      // e_bits = two's-complement low 5 bits of (E+15)  (matches floored
      // division + Python mod semantics for negative e_dec too);
      // m_bits = top 10 mantissa bits, truncated.
      w = ((unsigned)((E + 15) & 31) << 10) | (mant >> 13);
    }
    // sign: s = (sign(f + 0.001)*-1 + 1) * 0.5
    float tt = f + 0.001f;
    if (tt < 0.0f) {
      w |= 0x8000u;
    } else if (tt == 0.0f) {
      sign_half = true;  // s = 0.5 -> (s-0.5)*2 = 0.0
    }
  }

  int hi = 15 - 4 * c;  // bit positions hi..hi-3 map to outputs 4c..4c+3
  float4 o;
  o.x = ((w >> hi) & 1u) ? 1.0f : -1.0f;
  o.y = ((w >> (hi - 1)) & 1u) ? 1.0f : -1.0f;
  o.z = ((w >> (hi - 2)) & 1u) ? 1.0f : -1.0f;
  o.w = ((w >> (hi - 3)) & 1u) ? 1.0f : -1.0f;
  if (c == 0 && sign_half) o.x = 0.0f;

  out[t] = o;
}

extern "C" void kernel_launch(void* const* d_in, const int* in_sizes, int n_in,
                              void* d_out, int out_size, void* d_ws, size_t ws_size,
                              hipStream_t stream) {
  const float* x = (const float*)d_in[0];
  float4* out = (float4*)d_out;
  int n4 = out_size / 4;  // one float4 per thread
  int threads = 256;
  int blocks = (n4 + threads - 1) / threads;
  preencoder_f2b_kernel<<<blocks, threads, 0, stream>>>(x, out, n4);
}